// Round 6
// baseline (164.094 us; speedup 1.0000x reference)
//
#include <hip/hip_runtime.h>
#include <math.h>

typedef _Float16 half8v __attribute__((ext_vector_type(8)));
typedef _Float16 half4v __attribute__((ext_vector_type(4)));
typedef float float4v __attribute__((ext_vector_type(4)));

// ---- problem constants ----
#define BB    4096
#define NS    51
#define INV_ALPHA (1.0f/0.9f)

// ---- workspace float offsets ----
#define WS_CCW   0
#define WS_CCS   64
#define WS_LAM   128
#define WS_KEY64 160     // 64 uint slots (order-preserving max keys)
#define WS_PM    256     // 256 block-maxes of xm
#define WS_XM    512
#define WS_X     (WS_XM + BB)
#define WS_X2    (WS_X + BB)
#define WS_H     16384   // halfs region starts at byte 65536
// half offsets within WS_H
#define H_NET    8192
#define H_W2     4096
#define H_W0     16384   // + net*2048 : [64 j][32 k] zero-padded
#define H_W3     20480   // + net*64

#if defined(__has_builtin)
#if __has_builtin(__builtin_amdgcn_rcpf)
#define FRCP(x) __builtin_amdgcn_rcpf(x)
#endif
#endif
#ifndef FRCP
#define FRCP(x) (1.0f / (x))
#endif

__device__ __forceinline__ unsigned fkey(float f) {
    int i = __float_as_int(f);
    return (i >= 0) ? ((unsigned)i + 0x80000000u) : ~(unsigned)i;
}
__device__ __forceinline__ float fkey_inv(unsigned k) {
    return (k & 0x80000000u) ? __int_as_float((int)(k - 0x80000000u))
                             : __int_as_float((int)~k);
}

// act: 64 rows x 64 halfs, 16B column-blocks XOR-swizzled by row (bank spread)
__device__ __forceinline__ int swz(int row, int cb) {
    return (row << 6) + (((cb ^ (row & 7)) & 7) << 3);
}

// ---- fused setup: xm + 256 partial maxes | weight repack | CC + lam + keys ----
__global__ void k_setup(const float* __restrict__ x_, const float* __restrict__ lw,
                        const float* __restrict__ sp,
                        const float* __restrict__ f1W0, const float* __restrict__ f1W1,
                        const float* __restrict__ f1W2, const float* __restrict__ f1W3,
                        const float* __restrict__ f2W0, const float* __restrict__ f2W1,
                        const float* __restrict__ f2W2, const float* __restrict__ f2W3,
                        float* __restrict__ ws) {
    _Float16* wh = (_Float16*)(ws + WS_H);
    const int blk = blockIdx.x, tid = threadIdx.x;
    if (blk < 256) {
        int wave = tid >> 6, lane = tid & 63;
        float vmax = -1e30f;
        for (int r = 0; r < 4; ++r) {
            int row = blk * 16 + wave * 4 + r;
            float v = 0.0f;
            for (int i = lane; i < 100; i += 64) v = fmaf(x_[row * 100 + i], lw[i], v);
            #pragma unroll
            for (int off = 32; off > 0; off >>= 1) v += __shfl_xor(v, off, 64);
            if (lane == 0) ws[WS_XM + row] = v;
            vmax = fmaxf(vmax, v);
        }
        __shared__ float sm[4];
        if (lane == 0) sm[wave] = vmax;
        __syncthreads();
        if (tid == 0)
            ws[WS_PM + blk] = fmaxf(fmaxf(sm[0], sm[1]), fmaxf(sm[2], sm[3]));
    } else if (blk < 272) {
        int t = (blk - 256) * 256 + tid;       // 0..4095
        wh[t]                = (_Float16)f1W1[t];
        wh[H_W2 + t]         = (_Float16)f1W2[t];
        wh[H_NET + t]        = (_Float16)f2W1[t];
        wh[H_NET + H_W2 + t] = (_Float16)f2W2[t];
        if (t < 2048) {
            int j = t >> 5, k = t & 31;
            wh[H_W0 + t]        = (k < 5) ? (_Float16)f1W0[j * 5 + k] : (_Float16)0.0f;
            wh[H_W0 + 2048 + t] = (k < 5) ? (_Float16)f2W0[j * 5 + k] : (_Float16)0.0f;
        }
        if (t < 64) {
            wh[H_W3 + t]      = (_Float16)f1W3[t];
            wh[H_W3 + 64 + t] = (_Float16)f2W3[t];
        }
    } else {
        if (tid < 64) ((unsigned*)ws)[WS_KEY64 + tid] = 0u;   // key of -inf
        if (tid == 64) ws[WS_LAM] = 1.0f / (1.0f + expf(-sp[0]));
        if (tid >= 128 && tid <= 178) {
            int s = tid - 128;
            ws[WS_CCS + s] = cospif((float)s / 50.0f);
            float acc = 0.0f;
            for (int a = 0; a <= 50; ++a) {
                float w;
                if (a == 0) w = 1.0f;
                else if ((a & 1) == 0) w = 2.0f / (1.0f - (float)(a * a));
                else continue;
                float l;
                if (s == 0) l = 0.5f;
                else {
                    int m = (a * s) % 100;
                    l = cospif((float)m / 50.0f);
                    if (s == 50) l *= 0.5f;
                }
                acc += l * 0.04f * w;
            }
            ws[WS_CCW + s] = acc;
        }
    }
}

// Blocks [0,4096): I1 (f1, 0->x, b=blk). [4096,8192): I2 (f2, x2->xmax).
// [8192, +64): out_first (mode 1 only). One wave per block; lane = CC point / row.
__global__ __launch_bounds__(64) void k_int(
    int mode, float* __restrict__ ws, const float* __restrict__ h_,
    const float* __restrict__ f1b0, const float* __restrict__ f1b1,
    const float* __restrict__ f1b2, const float* __restrict__ f1b3,
    const float* __restrict__ f1Wf,
    const float* __restrict__ f2b0, const float* __restrict__ f2b1,
    const float* __restrict__ f2b2, const float* __restrict__ f2b3,
    const float* __restrict__ f2Wf,
    float* __restrict__ out)
{
    __shared__ _Float16 act[64 * 64];     // 8 KB, single wave, barrier-free

    const int blk = blockIdx.x;
    const int lane = threadIdx.x;         // 0..63
    const int lo = lane & 15, q = lane >> 4;

    const float* xm = ws + WS_XM;
    const float* xarr = ws + WS_X;
    const float* x2arr = ws + WS_X2;
    const _Float16* wh = (const _Float16*)(ws + WS_H);
    const float lam = ws[WS_LAM];
    const float oml = 1.0f - lam;

    int kind, b = 0, b0 = 0;
    if (blk < 4096)      { kind = 0; b = blk; }
    else if (blk < 8192) { kind = 1; b = blk - 4096; }
    else                 { kind = 2; b0 = (blk - 8192) * 64; b = b0 + lane; }

    // uniform per-row params
    float xmax = 0.0f, xb = 0.0f, x0 = 0.0f;
    float4 h4u = {0, 0, 0, 0};
    if (kind == 0) {
        xb = mode ? xarr[b] : oml * xm[b];
        h4u = ((const float4*)h_)[b];
    } else if (kind == 1) {
        if (mode) {
            float v = fkey_inv(((const unsigned*)ws)[WS_KEY64 + lane]);
            #pragma unroll
            for (int off = 32; off > 0; off >>= 1) v = fmaxf(v, __shfl_xor(v, off, 64));
            xmax = v + 10.0f;
        } else {
            const float* pm = ws + WS_PM;
            float v = fmaxf(fmaxf(pm[lane], pm[lane + 64]),
                            fmaxf(pm[lane + 128], pm[lane + 192]));
            #pragma unroll
            for (int off = 32; off > 0; off >>= 1) v = fmaxf(v, __shfl_xor(v, off, 64));
            xmax = oml * v + 10.0f;
        }
        x0 = mode ? x2arr[b] : oml * xm[b];
        h4u = ((const float4*)h_)[b];
    }

    const bool u2 = (kind == 1);
    const _Float16* W0h = wh + H_W0 + (u2 ? 2048 : 0);
    const _Float16* W1h = wh + (u2 ? H_NET : 0);
    const _Float16* W2h = W1h + H_W2;
    const _Float16* W3h = wh + H_W3 + (u2 ? 64 : 0);
    const float* B0 = u2 ? f2b0 : f1b0;
    const float* B1 = u2 ? f2b1 : f1b1;
    const float* B2 = u2 ? f2b2 : f1b2;
    const float* B3 = u2 ? f2b3 : f1b3;
    const float* WF = u2 ? f2Wf : f1Wf;
    const float p0 = u2 ? 1.5f : 1.1f;
    const float p1 = u2 ? 2.0f : 1.1f;
    const float p2 = u2 ? 2.5f : 1.5f;
    const float p3 = u2 ? 3.0f : 2.0f;
    const float p4 = u2 ? 3.5f : 2.5f;

    float4v accv[4][4];

    // ---- layer 0: 5(pad32)->64, B-operand built in registers (no LDS stage) ----
    {
        half8v Bf0[4];
        #pragma unroll
        for (int n = 0; n < 4; ++n) {
            int r = 16 * n + lo;                  // row (= CC point, or batch idx)
            float xr; float4 hr;
            if (kind == 2) {
                int idx = b0 + r;
                xr = x2arr[idx];
                hr = ((const float4*)h_)[idx];
            } else {
                int si = r > 50 ? 50 : r;
                float t = (ws[WS_CCS + si] + 1.0f) * 0.5f;
                xr = (kind == 0) ? xb * t : x0 + (xmax - x0) * t;
                hr = h4u;
            }
            half8v e;
            e[0] = (_Float16)xr; e[1] = (_Float16)hr.x; e[2] = (_Float16)hr.y;
            e[3] = (_Float16)hr.z; e[4] = (_Float16)hr.w;
            e[5] = (_Float16)0.0f; e[6] = (_Float16)0.0f; e[7] = (_Float16)0.0f;
            half8v z;
            #pragma unroll
            for (int t2 = 0; t2 < 8; ++t2) z[t2] = (_Float16)0.0f;
            Bf0[n] = (q == 0) ? e : z;
        }
        #pragma unroll
        for (int m = 0; m < 4; ++m) {
            half8v Af = *(const half8v*)(W0h + (16 * m + lo) * 32 + q * 8);
            float4v bb = *(const float4v*)(B0 + 16 * m + q * 4);
            #pragma unroll
            for (int n = 0; n < 4; ++n)
                accv[m][n] = __builtin_amdgcn_mfma_f32_16x16x32_f16(Af, Bf0[n], bb, 0, 0, 0);
        }
        #pragma unroll
        for (int m = 0; m < 4; ++m)
            #pragma unroll
            for (int n = 0; n < 4; ++n) {
                float4v c = accv[m][n];
                half4v o;
                o[0] = (_Float16)fmaxf(c[0], 0.0f); o[1] = (_Float16)fmaxf(c[1], 0.0f);
                o[2] = (_Float16)fmaxf(c[2], 0.0f); o[3] = (_Float16)fmaxf(c[3], 0.0f);
                *(half4v*)(act + swz(16 * n + lo, 2 * m + (q >> 1)) + 4 * (q & 1)) = o;
            }
    }

    // ---- layer 1: 64->64 (LDS round-trip) ----
    {
        half8v Bf[2][4];
        #pragma unroll
        for (int kb = 0; kb < 2; ++kb)
            #pragma unroll
            for (int n = 0; n < 4; ++n)
                Bf[kb][n] = *(const half8v*)(act + swz(16 * n + lo, 4 * kb + q));
        #pragma unroll
        for (int m = 0; m < 4; ++m) {
            float4v bb = *(const float4v*)(B1 + 16 * m + q * 4);
            half8v A0 = *(const half8v*)(W1h + (16 * m + lo) * 64 + q * 8);
            half8v A1 = *(const half8v*)(W1h + (16 * m + lo) * 64 + 32 + q * 8);
            #pragma unroll
            for (int n = 0; n < 4; ++n) {
                float4v c = bb;
                c = __builtin_amdgcn_mfma_f32_16x16x32_f16(A0, Bf[0][n], c, 0, 0, 0);
                c = __builtin_amdgcn_mfma_f32_16x16x32_f16(A1, Bf[1][n], c, 0, 0, 0);
                accv[m][n] = c;
            }
        }
        #pragma unroll
        for (int m = 0; m < 4; ++m)
            #pragma unroll
            for (int n = 0; n < 4; ++n) {
                float4v c = accv[m][n];
                half4v o;
                o[0] = (_Float16)fmaxf(c[0], 0.0f); o[1] = (_Float16)fmaxf(c[1], 0.0f);
                o[2] = (_Float16)fmaxf(c[2], 0.0f); o[3] = (_Float16)fmaxf(c[3], 0.0f);
                *(half4v*)(act + swz(16 * n + lo, 2 * m + (q >> 1)) + 4 * (q & 1)) = o;
            }
    }

    // ---- layer 2: 64->64, accumulators stay in registers ----
    {
        half8v Bf[2][4];
        #pragma unroll
        for (int kb = 0; kb < 2; ++kb)
            #pragma unroll
            for (int n = 0; n < 4; ++n)
                Bf[kb][n] = *(const half8v*)(act + swz(16 * n + lo, 4 * kb + q));
        #pragma unroll
        for (int m = 0; m < 4; ++m) {
            float4v bb = *(const float4v*)(B2 + 16 * m + q * 4);
            half8v A0 = *(const half8v*)(W2h + (16 * m + lo) * 64 + q * 8);
            half8v A1 = *(const half8v*)(W2h + (16 * m + lo) * 64 + 32 + q * 8);
            #pragma unroll
            for (int n = 0; n < 4; ++n) {
                float4v c = bb;
                c = __builtin_amdgcn_mfma_f32_16x16x32_f16(A0, Bf[0][n], c, 0, 0, 0);
                c = __builtin_amdgcn_mfma_f32_16x16x32_f16(A1, Bf[1][n], c, 0, 0, 0);
                accv[m][n] = c;
            }
        }
    }

    // ---- final 64->1 dot straight from accumulators (no LDS round-trip) ----
    // lane(q,lo) holds OUT[j=16m+4q+e][row=16n+lo]; partial over its j-subset,
    // then xor-reduce across quads to complete each row's dot.
    float part[4] = {0.0f, 0.0f, 0.0f, 0.0f};
    #pragma unroll
    for (int m = 0; m < 4; ++m) {
        half4v w3 = *(const half4v*)(W3h + 16 * m + 4 * q);
        #pragma unroll
        for (int n = 0; n < 4; ++n)
            #pragma unroll
            for (int e = 0; e < 4; ++e)
                part[n] = fmaf((float)w3[e], fmaxf(accv[m][n][e], 0.0f), part[n]);
    }
    #pragma unroll
    for (int n = 0; n < 4; ++n) {
        part[n] += __shfl_xor(part[n], 16, 64);
        part[n] += __shfl_xor(part[n], 32, 64);
    }
    float y = B3[0] + (q == 0 ? part[0] : q == 1 ? part[1] : q == 2 ? part[2] : part[3]);

    if (y <= 0.0f) y = __expf(y) - 1.0f;   // elu
    float z = y + 1.0f;
    float lg = __logf(z);
    float g = WF[0] * FRCP(__expf(p0 * lg) + 1.0f)
            + WF[1] * FRCP(__expf(p1 * lg) + 1.0f)
            + WF[2] * FRCP(__expf(p2 * lg) + 1.0f)
            + WF[3] * FRCP(__expf(p3 * lg) + 1.0f)
            + WF[4] * FRCP(__expf(p4 * lg) + 1.0f);
    float val = fmaxf(g, 0.0f);

    if (kind == 2) { out[BB + b] = val; return; }

    // quadrature: sum_s ccw[s]*val[s] via shuffle reduce
    float c = (lane <= 50) ? ws[WS_CCW + lane] * val : 0.0f;
    #pragma unroll
    for (int off = 32; off > 0; off >>= 1) c += __shfl_xor(c, off, 64);

    if (lane == 0) {
        if (kind == 0) {
            float I1 = c * xb * 0.5f;
            out[b] = I1;
            if (!mode) ws[WS_X + b] = oml * xm[b] + lam * I1;      // x for step1
        } else {
            float I2 = c * (xmax - x0) * 0.5f * INV_ALPHA;
            out[2 * BB + b] = I2;
            if (!mode) {
                float x2n = oml * xm[b] + lam * I2;                // x2 for step1
                ws[WS_X2 + b] = x2n;
                atomicMax((unsigned*)ws + WS_KEY64 + (b & 63), fkey(x2n));
            }
        }
    }
}

extern "C" void kernel_launch(void* const* d_in, const int* in_sizes, int n_in,
                              void* d_out, int out_size, void* d_ws, size_t ws_size,
                              hipStream_t stream) {
    const float* x_  = (const float*)d_in[0];
    const float* h_  = (const float*)d_in[1];
    const float* lw  = (const float*)d_in[2];
    const float* sp  = (const float*)d_in[3];
    const float* f1W0 = (const float*)d_in[4];   const float* f1b0 = (const float*)d_in[5];
    const float* f1W1 = (const float*)d_in[6];   const float* f1b1 = (const float*)d_in[7];
    const float* f1W2 = (const float*)d_in[8];   const float* f1b2 = (const float*)d_in[9];
    const float* f1W3 = (const float*)d_in[10];  const float* f1b3 = (const float*)d_in[11];
    const float* f1Wf = (const float*)d_in[12];
    const float* f2W0 = (const float*)d_in[13];  const float* f2b0 = (const float*)d_in[14];
    const float* f2W1 = (const float*)d_in[15];  const float* f2b1 = (const float*)d_in[16];
    const float* f2W2 = (const float*)d_in[17];  const float* f2b2 = (const float*)d_in[18];
    const float* f2W3 = (const float*)d_in[19];  const float* f2b3 = (const float*)d_in[20];
    const float* f2Wf = (const float*)d_in[21];
    float* out = (float*)d_out;
    float* ws  = (float*)d_ws;

    k_setup<<<273, 256, 0, stream>>>(x_, lw, sp,
                                     f1W0, f1W1, f1W2, f1W3,
                                     f2W0, f2W1, f2W2, f2W3, ws);
    k_int<<<8192, 64, 0, stream>>>(0, ws, h_,
        f1b0, f1b1, f1b2, f1b3, f1Wf, f2b0, f2b1, f2b2, f2b3, f2Wf, out);
    k_int<<<8256, 64, 0, stream>>>(1, ws, h_,
        f1b0, f1b1, f1b2, f1b3, f1Wf, f2b0, f2b1, f2b2, f2b3, f2Wf, out);
}

// Round 8
// 158.172 us; speedup vs baseline: 1.0374x; 1.0374x over previous
//
#include <hip/hip_runtime.h>
#include <math.h>

typedef _Float16 half8v __attribute__((ext_vector_type(8)));
typedef _Float16 half4v __attribute__((ext_vector_type(4)));
typedef _Float16 half2v __attribute__((ext_vector_type(2)));
typedef float float4v __attribute__((ext_vector_type(4)));

// ---- problem constants ----
#define BB    4096
#define NS    51
#define INV_ALPHA (1.0f/0.9f)

// ---- workspace float offsets ----
#define WS_CCW   0
#define WS_CCS   64
#define WS_LAM   128
#define WS_KEY64 160     // 64 uint slots (order-preserving max keys)
#define WS_PM    256     // 256 block-maxes of xm
#define WS_XM    512
#define WS_X     (WS_XM + BB)
#define WS_X2    (WS_X + BB)
#define WS_H     16384   // halfs region starts at byte 65536
// half offsets within WS_H
#define H_NET    8192
#define H_W2     4096
#define H_W0     16384   // + net*2048 : [64 j][32 k] zero-padded
#define H_W3     20480   // + net*64

#if defined(__has_builtin)
#if __has_builtin(__builtin_amdgcn_rcpf)
#define FRCP(x) __builtin_amdgcn_rcpf(x)
#endif
#if __has_builtin(__builtin_amdgcn_exp2f)
#define FEXP2(x) __builtin_amdgcn_exp2f(x)
#endif
#if __has_builtin(__builtin_amdgcn_logf)
#define FLOG2(x) __builtin_amdgcn_logf(x)
#endif
#endif
#ifndef FRCP
#define FRCP(x) (1.0f / (x))
#endif
#ifndef FEXP2
#define FEXP2(x) exp2f(x)
#endif
#ifndef FLOG2
#define FLOG2(x) log2f(x)
#endif

__device__ __forceinline__ unsigned fkey(float f) {
    int i = __float_as_int(f);
    return (i >= 0) ? ((unsigned)i + 0x80000000u) : ~(unsigned)i;
}
__device__ __forceinline__ float fkey_inv(unsigned k) {
    return (k & 0x80000000u) ? __int_as_float((int)(k - 0x80000000u))
                             : __int_as_float((int)~k);
}

// act: 64 rows x 64 halfs, 16B column-blocks XOR-swizzled by row (bank spread)
__device__ __forceinline__ int swz(int row, int cb) {
    return (row << 6) + (((cb ^ (row & 7)) & 7) << 3);
}

// relu + pack f32x4 -> f16x4
__device__ __forceinline__ half4v pk_relu4(float4v c) {
#if defined(__has_builtin) && __has_builtin(__builtin_amdgcn_cvt_pkrtz)
    half2v a = __builtin_bit_cast(half2v,
        __builtin_amdgcn_cvt_pkrtz(fmaxf(c[0], 0.0f), fmaxf(c[1], 0.0f)));
    half2v b = __builtin_bit_cast(half2v,
        __builtin_amdgcn_cvt_pkrtz(fmaxf(c[2], 0.0f), fmaxf(c[3], 0.0f)));
    half4v o; o[0] = a[0]; o[1] = a[1]; o[2] = b[0]; o[3] = b[1];
    return o;
#else
    half4v o;
    o[0] = (_Float16)fmaxf(c[0], 0.0f); o[1] = (_Float16)fmaxf(c[1], 0.0f);
    o[2] = (_Float16)fmaxf(c[2], 0.0f); o[3] = (_Float16)fmaxf(c[3], 0.0f);
    return o;
#endif
}

// ---- fused setup: xm + 256 partial maxes | weight repack | CC + lam + keys ----
__global__ void k_setup(const float* __restrict__ x_, const float* __restrict__ lw,
                        const float* __restrict__ sp,
                        const float* __restrict__ f1W0, const float* __restrict__ f1W1,
                        const float* __restrict__ f1W2, const float* __restrict__ f1W3,
                        const float* __restrict__ f2W0, const float* __restrict__ f2W1,
                        const float* __restrict__ f2W2, const float* __restrict__ f2W3,
                        float* __restrict__ ws) {
    _Float16* wh = (_Float16*)(ws + WS_H);
    const int blk = blockIdx.x, tid = threadIdx.x;
    if (blk < 256) {
        int wave = tid >> 6, lane = tid & 63;
        float vmax = -1e30f;
        for (int r = 0; r < 4; ++r) {
            int row = blk * 16 + wave * 4 + r;
            float v = 0.0f;
            for (int i = lane; i < 100; i += 64) v = fmaf(x_[row * 100 + i], lw[i], v);
            #pragma unroll
            for (int off = 32; off > 0; off >>= 1) v += __shfl_xor(v, off, 64);
            if (lane == 0) ws[WS_XM + row] = v;
            vmax = fmaxf(vmax, v);
        }
        __shared__ float sm[4];
        if (lane == 0) sm[wave] = vmax;
        __syncthreads();
        if (tid == 0)
            ws[WS_PM + blk] = fmaxf(fmaxf(sm[0], sm[1]), fmaxf(sm[2], sm[3]));
    } else if (blk < 272) {
        int t = (blk - 256) * 256 + tid;       // 0..4095
        wh[t]                = (_Float16)f1W1[t];
        wh[H_W2 + t]         = (_Float16)f1W2[t];
        wh[H_NET + t]        = (_Float16)f2W1[t];
        wh[H_NET + H_W2 + t] = (_Float16)f2W2[t];
        if (t < 2048) {
            int j = t >> 5, k = t & 31;
            wh[H_W0 + t]        = (k < 5) ? (_Float16)f1W0[j * 5 + k] : (_Float16)0.0f;
            wh[H_W0 + 2048 + t] = (k < 5) ? (_Float16)f2W0[j * 5 + k] : (_Float16)0.0f;
        }
        if (t < 64) {
            wh[H_W3 + t]      = (_Float16)f1W3[t];
            wh[H_W3 + 64 + t] = (_Float16)f2W3[t];
        }
    } else {
        if (tid < 64) ((unsigned*)ws)[WS_KEY64 + tid] = 0u;   // key of -inf
        if (tid == 64) ws[WS_LAM] = 1.0f / (1.0f + expf(-sp[0]));
        if (tid >= 128 && tid <= 178) {
            int s = tid - 128;
            ws[WS_CCS + s] = cospif((float)s / 50.0f);
            float acc = 0.0f;
            for (int a = 0; a <= 50; ++a) {
                float w;
                if (a == 0) w = 1.0f;
                else if ((a & 1) == 0) w = 2.0f / (1.0f - (float)(a * a));
                else continue;
                float l;
                if (s == 0) l = 0.5f;
                else {
                    int m = (a * s) % 100;
                    l = cospif((float)m / 50.0f);
                    if (s == 50) l *= 0.5f;
                }
                acc += l * 0.04f * w;
            }
            ws[WS_CCW + s] = acc;
        }
    }
}

// Blocks [0,4096): I1 (f1, 0->x, b=blk). [4096,8192): I2 (f2, x2->xmax).
// [8192, +64): out_first (mode 1 only). One wave per block; lane = CC point.
// Register-diet structure: per-m transient accumulators, W3-dot fused into L2.
__global__ __launch_bounds__(64, 4) void k_int(
    int mode, float* __restrict__ ws, const float* __restrict__ h_,
    const float* __restrict__ f1b0, const float* __restrict__ f1b1,
    const float* __restrict__ f1b2, const float* __restrict__ f1b3,
    const float* __restrict__ f1Wf,
    const float* __restrict__ f2b0, const float* __restrict__ f2b1,
    const float* __restrict__ f2b2, const float* __restrict__ f2b3,
    const float* __restrict__ f2Wf,
    float* __restrict__ out)
{
    __shared__ _Float16 act[64 * 64];     // 8 KB, single wave, barrier-free

    const int blk = blockIdx.x;
    const int lane = threadIdx.x;         // 0..63
    const int lo = lane & 15, q = lane >> 4;

    const float* xm = ws + WS_XM;
    const float* xarr = ws + WS_X;
    const float* x2arr = ws + WS_X2;
    const _Float16* wh = (const _Float16*)(ws + WS_H);
    const float lam = ws[WS_LAM];
    const float oml = 1.0f - lam;

    int kind, b = 0, b0 = 0;
    if (blk < 4096)      { kind = 0; b = blk; }
    else if (blk < 8192) { kind = 1; b = blk - 4096; }
    else                 { kind = 2; b0 = (blk - 8192) * 64; b = b0 + lane; }

    float xmax = 0.0f, xb = 0.0f, x0 = 0.0f;
    float4 h4u = {0, 0, 0, 0};
    if (kind == 0) {
        xb = mode ? xarr[b] : oml * xm[b];
        h4u = ((const float4*)h_)[b];
    } else if (kind == 1) {
        if (mode) {
            float v = fkey_inv(((const unsigned*)ws)[WS_KEY64 + lane]);
            #pragma unroll
            for (int off = 32; off > 0; off >>= 1) v = fmaxf(v, __shfl_xor(v, off, 64));
            xmax = v + 10.0f;
        } else {
            const float* pm = ws + WS_PM;
            float v = fmaxf(fmaxf(pm[lane], pm[lane + 64]),
                            fmaxf(pm[lane + 128], pm[lane + 192]));
            #pragma unroll
            for (int off = 32; off > 0; off >>= 1) v = fmaxf(v, __shfl_xor(v, off, 64));
            xmax = oml * v + 10.0f;
        }
        x0 = mode ? x2arr[b] : oml * xm[b];
        h4u = ((const float4*)h_)[b];
    }

    const bool u2 = (kind == 1);
    const _Float16* W0h = wh + H_W0 + (u2 ? 2048 : 0);
    const _Float16* W1h = wh + (u2 ? H_NET : 0);
    const _Float16* W2h = W1h + H_W2;
    const _Float16* W3h = wh + H_W3 + (u2 ? 64 : 0);
    const float* B0 = u2 ? f2b0 : f1b0;
    const float* B1 = u2 ? f2b1 : f1b1;
    const float* B2 = u2 ? f2b2 : f1b2;
    const float* B3 = u2 ? f2b3 : f1b3;
    const float* WF = u2 ? f2Wf : f1Wf;
    const float p0 = u2 ? 1.5f : 1.1f;
    const float p1 = u2 ? 2.0f : 1.1f;
    const float p2 = u2 ? 2.5f : 1.5f;
    const float p3 = u2 ? 3.0f : 2.0f;
    const float p4 = u2 ? 3.5f : 2.5f;

    // ---- layer 0: 5(pad32)->64; B built in regs; per-m transient acc ----
    {
        half8v Bf0[4];
        #pragma unroll
        for (int n = 0; n < 4; ++n) {
            int r = 16 * n + lo;                  // row (= CC point, or batch idx)
            float xr; float4 hr;
            if (kind == 2) {
                int idx = b0 + r;
                xr = x2arr[idx];
                hr = ((const float4*)h_)[idx];
            } else {
                int si = r > 50 ? 50 : r;
                float t = (ws[WS_CCS + si] + 1.0f) * 0.5f;
                xr = (kind == 0) ? xb * t : x0 + (xmax - x0) * t;
                hr = h4u;
            }
            half8v e;
            e[0] = (_Float16)xr; e[1] = (_Float16)hr.x; e[2] = (_Float16)hr.y;
            e[3] = (_Float16)hr.z; e[4] = (_Float16)hr.w;
            e[5] = (_Float16)0.0f; e[6] = (_Float16)0.0f; e[7] = (_Float16)0.0f;
            half8v z;
            #pragma unroll
            for (int t2 = 0; t2 < 8; ++t2) z[t2] = (_Float16)0.0f;
            Bf0[n] = (q == 0) ? e : z;
        }
        #pragma unroll
        for (int m = 0; m < 4; ++m) {
            half8v Af = *(const half8v*)(W0h + (16 * m + lo) * 32 + q * 8);
            float4v bb = *(const float4v*)(B0 + 16 * m + q * 4);
            #pragma unroll
            for (int n = 0; n < 4; ++n) {
                float4v c = __builtin_amdgcn_mfma_f32_16x16x32_f16(Af, Bf0[n], bb, 0, 0, 0);
                *(half4v*)(act + swz(16 * n + lo, 2 * m + (q >> 1)) + 4 * (q & 1)) = pk_relu4(c);
            }
        }
    }

    // ---- layer 1: 64->64; per-m transient acc ----
    {
        half8v Bf[2][4];
        #pragma unroll
        for (int kb = 0; kb < 2; ++kb)
            #pragma unroll
            for (int n = 0; n < 4; ++n)
                Bf[kb][n] = *(const half8v*)(act + swz(16 * n + lo, 4 * kb + q));
        #pragma unroll
        for (int m = 0; m < 4; ++m) {
            half8v A0 = *(const half8v*)(W1h + (16 * m + lo) * 64 + q * 8);
            half8v A1 = *(const half8v*)(W1h + (16 * m + lo) * 64 + 32 + q * 8);
            float4v bb = *(const float4v*)(B1 + 16 * m + q * 4);
            #pragma unroll
            for (int n = 0; n < 4; ++n) {
                float4v c = __builtin_amdgcn_mfma_f32_16x16x32_f16(A0, Bf[0][n], bb, 0, 0, 0);
                c = __builtin_amdgcn_mfma_f32_16x16x32_f16(A1, Bf[1][n], c, 0, 0, 0);
                *(half4v*)(act + swz(16 * n + lo, 2 * m + (q >> 1)) + 4 * (q & 1)) = pk_relu4(c);
            }
        }
    }

    // ---- layer 2: 64->64 with W3-dot fused (no output kept) ----
    float part[4] = {0.0f, 0.0f, 0.0f, 0.0f};
    {
        half8v Bf[2][4];
        #pragma unroll
        for (int kb = 0; kb < 2; ++kb)
            #pragma unroll
            for (int n = 0; n < 4; ++n)
                Bf[kb][n] = *(const half8v*)(act + swz(16 * n + lo, 4 * kb + q));
        #pragma unroll
        for (int m = 0; m < 4; ++m) {
            half8v A0 = *(const half8v*)(W2h + (16 * m + lo) * 64 + q * 8);
            half8v A1 = *(const half8v*)(W2h + (16 * m + lo) * 64 + 32 + q * 8);
            float4v bb = *(const float4v*)(B2 + 16 * m + q * 4);
            half4v w3 = *(const half4v*)(W3h + 16 * m + 4 * q);
            #pragma unroll
            for (int n = 0; n < 4; ++n) {
                float4v c = __builtin_amdgcn_mfma_f32_16x16x32_f16(A0, Bf[0][n], bb, 0, 0, 0);
                c = __builtin_amdgcn_mfma_f32_16x16x32_f16(A1, Bf[1][n], c, 0, 0, 0);
                #pragma unroll
                for (int e = 0; e < 4; ++e)
                    part[n] = fmaf((float)w3[e], fmaxf(c[e], 0.0f), part[n]);
            }
        }
    }

    // cross-quad reduce: lane(lo,q) ends with y for row = 16q+lo = lane
    #pragma unroll
    for (int n = 0; n < 4; ++n) {
        part[n] += __shfl_xor(part[n], 16, 64);
        part[n] += __shfl_xor(part[n], 32, 64);
    }
    float y = B3[0] + (q == 0 ? part[0] : q == 1 ? part[1] : q == 2 ? part[2] : part[3]);

    if (y <= 0.0f) y = FEXP2(y * 1.44269504f) - 1.0f;   // elu
    float z = y + 1.0f;
    float lg = FLOG2(z);         // z=0 -> -inf -> exp2 -> 0 (matches 0**p)
    float g = WF[0] * FRCP(FEXP2(p0 * lg) + 1.0f)
            + WF[1] * FRCP(FEXP2(p1 * lg) + 1.0f)
            + WF[2] * FRCP(FEXP2(p2 * lg) + 1.0f)
            + WF[3] * FRCP(FEXP2(p3 * lg) + 1.0f)
            + WF[4] * FRCP(FEXP2(p4 * lg) + 1.0f);
    float val = fmaxf(g, 0.0f);

    if (kind == 2) { out[BB + b] = val; return; }

    // quadrature: sum_s ccw[s]*val[s] via shuffle reduce
    float c = (lane <= 50) ? ws[WS_CCW + lane] * val : 0.0f;
    #pragma unroll
    for (int off = 32; off > 0; off >>= 1) c += __shfl_xor(c, off, 64);

    if (lane == 0) {
        if (kind == 0) {
            float I1 = c * xb * 0.5f;
            out[b] = I1;
            if (!mode) ws[WS_X + b] = oml * xm[b] + lam * I1;      // x for step1
        } else {
            float I2 = c * (xmax - x0) * 0.5f * INV_ALPHA;
            out[2 * BB + b] = I2;
            if (!mode) {
                float x2n = oml * xm[b] + lam * I2;                // x2 for step1
                ws[WS_X2 + b] = x2n;
                atomicMax((unsigned*)ws + WS_KEY64 + (b & 63), fkey(x2n));
            }
        }
    }
}

extern "C" void kernel_launch(void* const* d_in, const int* in_sizes, int n_in,
                              void* d_out, int out_size, void* d_ws, size_t ws_size,
                              hipStream_t stream) {
    const float* x_  = (const float*)d_in[0];
    const float* h_  = (const float*)d_in[1];
    const float* lw  = (const float*)d_in[2];
    const float* sp  = (const float*)d_in[3];
    const float* f1W0 = (const float*)d_in[4];   const float* f1b0 = (const float*)d_in[5];
    const float* f1W1 = (const float*)d_in[6];   const float* f1b1 = (const float*)d_in[7];
    const float* f1W2 = (const float*)d_in[8];   const float* f1b2 = (const float*)d_in[9];
    const float* f1W3 = (const float*)d_in[10];  const float* f1b3 = (const float*)d_in[11];
    const float* f1Wf = (const float*)d_in[12];
    const float* f2W0 = (const float*)d_in[13];  const float* f2b0 = (const float*)d_in[14];
    const float* f2W1 = (const float*)d_in[15];  const float* f2b1 = (const float*)d_in[16];
    const float* f2W2 = (const float*)d_in[17];  const float* f2b2 = (const float*)d_in[18];
    const float* f2W3 = (const float*)d_in[19];  const float* f2b3 = (const float*)d_in[20];
    const float* f2Wf = (const float*)d_in[21];
    float* out = (float*)d_out;
    float* ws  = (float*)d_ws;

    k_setup<<<273, 256, 0, stream>>>(x_, lw, sp,
                                     f1W0, f1W1, f1W2, f1W3,
                                     f2W0, f2W1, f2W2, f2W3, ws);
    k_int<<<8192, 64, 0, stream>>>(0, ws, h_,
        f1b0, f1b1, f1b2, f1b3, f1Wf, f2b0, f2b1, f2b2, f2b3, f2Wf, out);
    k_int<<<8256, 64, 0, stream>>>(1, ws, h_,
        f1b0, f1b1, f1b2, f1b3, f1Wf, f2b0, f2b1, f2b2, f2b3, f2Wf, out);
}

// Round 9
// 144.935 us; speedup vs baseline: 1.1322x; 1.0913x over previous
//
#include <hip/hip_runtime.h>
#include <math.h>

typedef _Float16 half8v __attribute__((ext_vector_type(8)));
typedef _Float16 half4v __attribute__((ext_vector_type(4)));
typedef _Float16 half2v __attribute__((ext_vector_type(2)));
typedef float float4v __attribute__((ext_vector_type(4)));

// ---- problem constants ----
#define BB    4096
#define NS    51
#define INV_ALPHA (1.0f/0.9f)

// ---- workspace float offsets ----
#define WS_CCW   0
#define WS_CCS   64
#define WS_LAM   128
#define WS_KEY64 160     // 64 uint slots (order-preserving max keys)
#define WS_PM    256     // 256 block-maxes of xm
#define WS_XM    512
#define WS_X     (WS_XM + BB)
#define WS_X2    (WS_X + BB)
#define WS_H     16384   // halfs region starts at byte 65536
// half offsets within WS_H
#define H_NET    8192
#define H_W2     4096
#define H_W0     16384   // + net*2048 : [64 j][32 k] zero-padded
#define H_W3     20480   // + net*64

#if defined(__has_builtin)
#if __has_builtin(__builtin_amdgcn_rcpf)
#define FRCP(x) __builtin_amdgcn_rcpf(x)
#endif
#if __has_builtin(__builtin_amdgcn_exp2f)
#define FEXP2(x) __builtin_amdgcn_exp2f(x)
#endif
#if __has_builtin(__builtin_amdgcn_logf)
#define FLOG2(x) __builtin_amdgcn_logf(x)
#endif
#endif
#ifndef FRCP
#define FRCP(x) (1.0f / (x))
#endif
#ifndef FEXP2
#define FEXP2(x) exp2f(x)
#endif
#ifndef FLOG2
#define FLOG2(x) log2f(x)
#endif

__device__ __forceinline__ unsigned fkey(float f) {
    int i = __float_as_int(f);
    return (i >= 0) ? ((unsigned)i + 0x80000000u) : ~(unsigned)i;
}
__device__ __forceinline__ float fkey_inv(unsigned k) {
    return (k & 0x80000000u) ? __int_as_float((int)(k - 0x80000000u))
                             : __int_as_float((int)~k);
}

// act: 64 rows x 64 halfs, 16B column-blocks XOR-swizzled by row
__device__ __forceinline__ int swz(int row, int cb) {
    return (row << 6) + (((cb ^ (row & 7)) & 7) << 3);
}

// relu + pack f32x4 -> f16x4
__device__ __forceinline__ half4v pk_relu4(float4v c) {
#if defined(__has_builtin) && __has_builtin(__builtin_amdgcn_cvt_pkrtz)
    half2v a = __builtin_bit_cast(half2v,
        __builtin_amdgcn_cvt_pkrtz(fmaxf(c[0], 0.0f), fmaxf(c[1], 0.0f)));
    half2v b = __builtin_bit_cast(half2v,
        __builtin_amdgcn_cvt_pkrtz(fmaxf(c[2], 0.0f), fmaxf(c[3], 0.0f)));
    half4v o; o[0] = a[0]; o[1] = a[1]; o[2] = b[0]; o[3] = b[1];
    return o;
#else
    half4v o;
    o[0] = (_Float16)fmaxf(c[0], 0.0f); o[1] = (_Float16)fmaxf(c[1], 0.0f);
    o[2] = (_Float16)fmaxf(c[2], 0.0f); o[3] = (_Float16)fmaxf(c[3], 0.0f);
    return o;
#endif
}

// ---- fused setup: xm + 256 partial maxes | weight repack | CC + lam + keys ----
__global__ void k_setup(const float* __restrict__ x_, const float* __restrict__ lw,
                        const float* __restrict__ sp,
                        const float* __restrict__ f1W0, const float* __restrict__ f1W1,
                        const float* __restrict__ f1W2, const float* __restrict__ f1W3,
                        const float* __restrict__ f2W0, const float* __restrict__ f2W1,
                        const float* __restrict__ f2W2, const float* __restrict__ f2W3,
                        float* __restrict__ ws) {
    _Float16* wh = (_Float16*)(ws + WS_H);
    const int blk = blockIdx.x, tid = threadIdx.x;
    if (blk < 256) {
        int wave = tid >> 6, lane = tid & 63;
        float vmax = -1e30f;
        for (int r = 0; r < 4; ++r) {
            int row = blk * 16 + wave * 4 + r;
            float v = 0.0f;
            for (int i = lane; i < 100; i += 64) v = fmaf(x_[row * 100 + i], lw[i], v);
            #pragma unroll
            for (int off = 32; off > 0; off >>= 1) v += __shfl_xor(v, off, 64);
            if (lane == 0) ws[WS_XM + row] = v;
            vmax = fmaxf(vmax, v);
        }
        __shared__ float sm[4];
        if (lane == 0) sm[wave] = vmax;
        __syncthreads();
        if (tid == 0)
            ws[WS_PM + blk] = fmaxf(fmaxf(sm[0], sm[1]), fmaxf(sm[2], sm[3]));
    } else if (blk < 272) {
        int t = (blk - 256) * 256 + tid;       // 0..4095
        wh[t]                = (_Float16)f1W1[t];
        wh[H_W2 + t]         = (_Float16)f1W2[t];
        wh[H_NET + t]        = (_Float16)f2W1[t];
        wh[H_NET + H_W2 + t] = (_Float16)f2W2[t];
        if (t < 2048) {
            int j = t >> 5, k = t & 31;
            wh[H_W0 + t]        = (k < 5) ? (_Float16)f1W0[j * 5 + k] : (_Float16)0.0f;
            wh[H_W0 + 2048 + t] = (k < 5) ? (_Float16)f2W0[j * 5 + k] : (_Float16)0.0f;
        }
        if (t < 64) {
            wh[H_W3 + t]      = (_Float16)f1W3[t];
            wh[H_W3 + 64 + t] = (_Float16)f2W3[t];
        }
    } else {
        if (tid < 64) ((unsigned*)ws)[WS_KEY64 + tid] = 0u;   // key of -inf
        if (tid == 64) ws[WS_LAM] = 1.0f / (1.0f + expf(-sp[0]));
        if (tid >= 128 && tid <= 178) {
            int s = tid - 128;
            ws[WS_CCS + s] = cospif((float)s / 50.0f);
            float acc = 0.0f;
            for (int a = 0; a <= 50; ++a) {
                float w;
                if (a == 0) w = 1.0f;
                else if ((a & 1) == 0) w = 2.0f / (1.0f - (float)(a * a));
                else continue;
                float l;
                if (s == 0) l = 0.5f;
                else {
                    int m = (a * s) % 100;
                    l = cospif((float)m / 50.0f);
                    if (s == 50) l *= 0.5f;
                }
                acc += l * 0.04f * w;
            }
            ws[WS_CCW + s] = acc;
        }
    }
}

// Persistent one-wave blocks: blk<1024 -> f1/I1 (4 items b=blk+1024*it);
// blk>=1024 -> f2/I2. Blocks 0..63 additionally do out_first in mode 1.
// All weight fragments + biases held in VGPRs across items.
__global__ __launch_bounds__(64, 2) void k_int(
    int mode, float* __restrict__ ws, const float* __restrict__ h_,
    const float* __restrict__ f1b0, const float* __restrict__ f1b1,
    const float* __restrict__ f1b2, const float* __restrict__ f1b3,
    const float* __restrict__ f1Wf,
    const float* __restrict__ f2b0, const float* __restrict__ f2b1,
    const float* __restrict__ f2b2, const float* __restrict__ f2b3,
    const float* __restrict__ f2Wf,
    float* __restrict__ out)
{
    __shared__ _Float16 act[64 * 64];     // 8 KB, single wave, barrier-free

    const int blk = blockIdx.x;
    const int lane = threadIdx.x;         // 0..63
    const int lo = lane & 15, q = lane >> 4;

    const float* xm = ws + WS_XM;
    const float* xarr = ws + WS_X;
    const float* x2arr = ws + WS_X2;
    const _Float16* wh = (const _Float16*)(ws + WS_H);
    const float lam = ws[WS_LAM];
    const float oml = 1.0f - lam;

    const bool u2 = (blk >= 1024);
    const int kb0 = u2 ? blk - 1024 : blk;

    const _Float16* W0h = wh + H_W0 + (u2 ? 2048 : 0);
    const _Float16* W1h = wh + (u2 ? H_NET : 0);
    const _Float16* W2h = W1h + H_W2;
    const _Float16* W3h = wh + H_W3 + (u2 ? 64 : 0);
    const float* B0 = u2 ? f2b0 : f1b0;
    const float* B1 = u2 ? f2b1 : f1b1;
    const float* B2 = u2 ? f2b2 : f1b2;
    const float* B3 = u2 ? f2b3 : f1b3;
    const float* WF = u2 ? f2Wf : f1Wf;
    const float p0 = u2 ? 1.5f : 1.1f;
    const float p1 = u2 ? 2.0f : 1.1f;
    const float p2 = u2 ? 2.5f : 1.5f;
    const float p3 = u2 ? 3.0f : 2.0f;
    const float p4 = u2 ? 3.5f : 2.5f;

    // ---- pin all weights/biases in registers (once per block) ----
    half8v A0w[4], A1w[4][2], A2w[4][2];
    float4v b0r[4], b1r[4], b2r[4];
    half4v w3r[4];
    #pragma unroll
    for (int m = 0; m < 4; ++m) {
        A0w[m]    = *(const half8v*)(W0h + (16 * m + lo) * 32 + q * 8);
        A1w[m][0] = *(const half8v*)(W1h + (16 * m + lo) * 64 + q * 8);
        A1w[m][1] = *(const half8v*)(W1h + (16 * m + lo) * 64 + 32 + q * 8);
        A2w[m][0] = *(const half8v*)(W2h + (16 * m + lo) * 64 + q * 8);
        A2w[m][1] = *(const half8v*)(W2h + (16 * m + lo) * 64 + 32 + q * 8);
        b0r[m] = *(const float4v*)(B0 + 16 * m + q * 4);
        b1r[m] = *(const float4v*)(B1 + 16 * m + q * 4);
        b2r[m] = *(const float4v*)(B2 + 16 * m + q * 4);
        w3r[m] = *(const half4v*)(W3h + 16 * m + 4 * q);
    }
    const float B3s = B3[0];
    const float wf0 = WF[0], wf1 = WF[1], wf2 = WF[2], wf3 = WF[3], wf4 = WF[4];

    // ---- hoisted uniforms ----
    float t_r[4];
    #pragma unroll
    for (int n = 0; n < 4; ++n) {
        int r = 16 * n + lo;
        t_r[n] = (ws[WS_CCS + (r > 50 ? 50 : r)] + 1.0f) * 0.5f;
    }
    const float ccw_l = (lane <= 50) ? ws[WS_CCW + lane] : 0.0f;

    float xmax = 0.0f;
    if (u2) {
        if (mode) {
            float v = fkey_inv(((const unsigned*)ws)[WS_KEY64 + lane]);
            #pragma unroll
            for (int off = 32; off > 0; off >>= 1) v = fmaxf(v, __shfl_xor(v, off, 64));
            xmax = v + 10.0f;
        } else {
            const float* pm = ws + WS_PM;
            float v = fmaxf(fmaxf(pm[lane], pm[lane + 64]),
                            fmaxf(pm[lane + 128], pm[lane + 192]));
            #pragma unroll
            for (int off = 32; off > 0; off >>= 1) v = fmaxf(v, __shfl_xor(v, off, 64));
            xmax = oml * v + 10.0f;
        }
    }

    const int nitems = (mode && !u2 && blk < 64) ? 5 : 4;

    #pragma clang loop unroll(disable)
    for (int it = 0; it < nitems; ++it) {
        const bool last = (it == 4);          // out_first item (f1 weights)
        int b = kb0 + 1024 * it;
        float xb = 0.0f, x0 = 0.0f;
        float4 h4u = {0, 0, 0, 0};

        half8v Bf0[4];
        if (last) {
            int b0i = blk * 64;
            #pragma unroll
            for (int n = 0; n < 4; ++n) {
                int idx = b0i + 16 * n + lo;
                float xr = x2arr[idx];
                float4 hr = ((const float4*)h_)[idx];
                half8v e;
                e[0] = (_Float16)xr; e[1] = (_Float16)hr.x; e[2] = (_Float16)hr.y;
                e[3] = (_Float16)hr.z; e[4] = (_Float16)hr.w;
                e[5] = (_Float16)0.0f; e[6] = (_Float16)0.0f; e[7] = (_Float16)0.0f;
                half8v z;
                #pragma unroll
                for (int t2 = 0; t2 < 8; ++t2) z[t2] = (_Float16)0.0f;
                Bf0[n] = (q == 0) ? e : z;
            }
        } else {
            if (!u2) xb = mode ? xarr[b] : oml * xm[b];
            else     x0 = mode ? x2arr[b] : oml * xm[b];
            h4u = ((const float4*)h_)[b];
            #pragma unroll
            for (int n = 0; n < 4; ++n) {
                float xr = (!u2) ? xb * t_r[n] : x0 + (xmax - x0) * t_r[n];
                half8v e;
                e[0] = (_Float16)xr; e[1] = (_Float16)h4u.x; e[2] = (_Float16)h4u.y;
                e[3] = (_Float16)h4u.z; e[4] = (_Float16)h4u.w;
                e[5] = (_Float16)0.0f; e[6] = (_Float16)0.0f; e[7] = (_Float16)0.0f;
                half8v z;
                #pragma unroll
                for (int t2 = 0; t2 < 8; ++t2) z[t2] = (_Float16)0.0f;
                Bf0[n] = (q == 0) ? e : z;
            }
        }

        // ---- layer 0 ----
        #pragma unroll
        for (int m = 0; m < 4; ++m)
            #pragma unroll
            for (int n = 0; n < 4; ++n) {
                float4v c = __builtin_amdgcn_mfma_f32_16x16x32_f16(A0w[m], Bf0[n], b0r[m], 0, 0, 0);
                *(half4v*)(act + swz(16 * n + lo, 2 * m + (q >> 1)) + 4 * (q & 1)) = pk_relu4(c);
            }

        // ---- layer 1 ----
        {
            half8v Bf[2][4];
            #pragma unroll
            for (int kb = 0; kb < 2; ++kb)
                #pragma unroll
                for (int n = 0; n < 4; ++n)
                    Bf[kb][n] = *(const half8v*)(act + swz(16 * n + lo, 4 * kb + q));
            #pragma unroll
            for (int m = 0; m < 4; ++m)
                #pragma unroll
                for (int n = 0; n < 4; ++n) {
                    float4v c = __builtin_amdgcn_mfma_f32_16x16x32_f16(A1w[m][0], Bf[0][n], b1r[m], 0, 0, 0);
                    c = __builtin_amdgcn_mfma_f32_16x16x32_f16(A1w[m][1], Bf[1][n], c, 0, 0, 0);
                    *(half4v*)(act + swz(16 * n + lo, 2 * m + (q >> 1)) + 4 * (q & 1)) = pk_relu4(c);
                }
        }

        // ---- layer 2 with fused W3-dot ----
        float part[4] = {0.0f, 0.0f, 0.0f, 0.0f};
        {
            half8v Bf[2][4];
            #pragma unroll
            for (int kb = 0; kb < 2; ++kb)
                #pragma unroll
                for (int n = 0; n < 4; ++n)
                    Bf[kb][n] = *(const half8v*)(act + swz(16 * n + lo, 4 * kb + q));
            #pragma unroll
            for (int m = 0; m < 4; ++m)
                #pragma unroll
                for (int n = 0; n < 4; ++n) {
                    float4v c = __builtin_amdgcn_mfma_f32_16x16x32_f16(A2w[m][0], Bf[0][n], b2r[m], 0, 0, 0);
                    c = __builtin_amdgcn_mfma_f32_16x16x32_f16(A2w[m][1], Bf[1][n], c, 0, 0, 0);
                    #pragma unroll
                    for (int e = 0; e < 4; ++e)
                        part[n] = fmaf((float)w3r[m][e], fmaxf(c[e], 0.0f), part[n]);
                }
        }

        #pragma unroll
        for (int n = 0; n < 4; ++n) {
            part[n] += __shfl_xor(part[n], 16, 64);
            part[n] += __shfl_xor(part[n], 32, 64);
        }
        float y = B3s + (q == 0 ? part[0] : q == 1 ? part[1] : q == 2 ? part[2] : part[3]);

        if (y <= 0.0f) y = FEXP2(y * 1.44269504f) - 1.0f;   // elu
        float z = y + 1.0f;
        float lg = FLOG2(z);
        float g = wf0 * FRCP(FEXP2(p0 * lg) + 1.0f)
                + wf1 * FRCP(FEXP2(p1 * lg) + 1.0f)
                + wf2 * FRCP(FEXP2(p2 * lg) + 1.0f)
                + wf3 * FRCP(FEXP2(p3 * lg) + 1.0f)
                + wf4 * FRCP(FEXP2(p4 * lg) + 1.0f);
        float val = fmaxf(g, 0.0f);

        if (last) {
            out[BB + blk * 64 + lane] = val;
            continue;
        }

        // quadrature: sum_s ccw[s]*val[s]
        float c = ccw_l * val;
        #pragma unroll
        for (int off = 32; off > 0; off >>= 1) c += __shfl_xor(c, off, 64);

        if (lane == 0) {
            if (!u2) {
                float I1 = c * xb * 0.5f;
                out[b] = I1;
                if (!mode) ws[WS_X + b] = oml * xm[b] + lam * I1;     // x for step1
            } else {
                float I2 = c * (xmax - x0) * 0.5f * INV_ALPHA;
                out[2 * BB + b] = I2;
                if (!mode) {
                    float x2n = oml * xm[b] + lam * I2;               // x2 for step1
                    ws[WS_X2 + b] = x2n;
                    atomicMax((unsigned*)ws + WS_KEY64 + (b & 63), fkey(x2n));
                }
            }
        }
    }
}

extern "C" void kernel_launch(void* const* d_in, const int* in_sizes, int n_in,
                              void* d_out, int out_size, void* d_ws, size_t ws_size,
                              hipStream_t stream) {
    const float* x_  = (const float*)d_in[0];
    const float* h_  = (const float*)d_in[1];
    const float* lw  = (const float*)d_in[2];
    const float* sp  = (const float*)d_in[3];
    const float* f1W0 = (const float*)d_in[4];   const float* f1b0 = (const float*)d_in[5];
    const float* f1W1 = (const float*)d_in[6];   const float* f1b1 = (const float*)d_in[7];
    const float* f1W2 = (const float*)d_in[8];   const float* f1b2 = (const float*)d_in[9];
    const float* f1W3 = (const float*)d_in[10];  const float* f1b3 = (const float*)d_in[11];
    const float* f1Wf = (const float*)d_in[12];
    const float* f2W0 = (const float*)d_in[13];  const float* f2b0 = (const float*)d_in[14];
    const float* f2W1 = (const float*)d_in[15];  const float* f2b1 = (const float*)d_in[16];
    const float* f2W2 = (const float*)d_in[17];  const float* f2b2 = (const float*)d_in[18];
    const float* f2W3 = (const float*)d_in[19];  const float* f2b3 = (const float*)d_in[20];
    const float* f2Wf = (const float*)d_in[21];
    float* out = (float*)d_out;
    float* ws  = (float*)d_ws;

    k_setup<<<273, 256, 0, stream>>>(x_, lw, sp,
                                     f1W0, f1W1, f1W2, f1W3,
                                     f2W0, f2W1, f2W2, f2W3, ws);
    k_int<<<2048, 64, 0, stream>>>(0, ws, h_,
        f1b0, f1b1, f1b2, f1b3, f1Wf, f2b0, f2b1, f2b2, f2b3, f2Wf, out);
    k_int<<<2048, 64, 0, stream>>>(1, ws, h_,
        f1b0, f1b1, f1b2, f1b3, f1Wf, f2b0, f2b1, f2b2, f2b3, f2Wf, out);
}

// Round 10
// 143.274 us; speedup vs baseline: 1.1453x; 1.0116x over previous
//
#include <hip/hip_runtime.h>
#include <math.h>

typedef _Float16 half8v __attribute__((ext_vector_type(8)));
typedef _Float16 half4v __attribute__((ext_vector_type(4)));
typedef _Float16 half2v __attribute__((ext_vector_type(2)));
typedef float float4v __attribute__((ext_vector_type(4)));

// ---- problem constants ----
#define BB    4096
#define INV_ALPHA (1.0f/0.9f)

// ---- workspace float offsets ----
#define WS_CCW  0
#define WS_CCS  64
#define WS_LAM  128
#define WS_PM16 160     // 16 block-maxes of x2_step1 (written by k_pre)
#define WS_PM   256     // 256 block-maxes of xm
#define WS_XM   512
#define WS_X    (WS_XM + BB)
#define WS_X2   (WS_X + BB)
#define WS_H    16384   // halfs region starts at byte 65536
// half offsets within WS_H
#define H_NET   8192
#define H_W2    4096
#define H_W0    16384   // + net*2048 : [64 j][32 k] zero-padded
#define H_W3    20480   // + net*64

#if defined(__has_builtin)
#if __has_builtin(__builtin_amdgcn_rcpf)
#define FRCP(x) __builtin_amdgcn_rcpf(x)
#endif
#if __has_builtin(__builtin_amdgcn_exp2f)
#define FEXP2(x) __builtin_amdgcn_exp2f(x)
#endif
#if __has_builtin(__builtin_amdgcn_logf)
#define FLOG2(x) __builtin_amdgcn_logf(x)
#endif
#endif
#ifndef FRCP
#define FRCP(x) (1.0f / (x))
#endif
#ifndef FEXP2
#define FEXP2(x) exp2f(x)
#endif
#ifndef FLOG2
#define FLOG2(x) log2f(x)
#endif

// act: 64 rows x 64 halfs, 16B column-blocks XOR-swizzled by row
__device__ __forceinline__ int swz(int row, int cb) {
    return (row << 6) + (((cb ^ (row & 7)) & 7) << 3);
}

// relu + pack f32x4 -> f16x4
__device__ __forceinline__ half4v pk_relu4(float4v c) {
#if defined(__has_builtin) && __has_builtin(__builtin_amdgcn_cvt_pkrtz)
    half2v a = __builtin_bit_cast(half2v,
        __builtin_amdgcn_cvt_pkrtz(fmaxf(c[0], 0.0f), fmaxf(c[1], 0.0f)));
    half2v b = __builtin_bit_cast(half2v,
        __builtin_amdgcn_cvt_pkrtz(fmaxf(c[2], 0.0f), fmaxf(c[3], 0.0f)));
    half4v o; o[0] = a[0]; o[1] = a[1]; o[2] = b[0]; o[3] = b[1];
    return o;
#else
    half4v o;
    o[0] = (_Float16)fmaxf(c[0], 0.0f); o[1] = (_Float16)fmaxf(c[1], 0.0f);
    o[2] = (_Float16)fmaxf(c[2], 0.0f); o[3] = (_Float16)fmaxf(c[3], 0.0f);
    return o;
#endif
}

// ---- fused setup: xm + maxes | weight repack | CC + lam | zero accumulators ----
__global__ void k_setup(const float* __restrict__ x_, const float* __restrict__ lw,
                        const float* __restrict__ sp,
                        const float* __restrict__ f1W0, const float* __restrict__ f1W1,
                        const float* __restrict__ f1W2, const float* __restrict__ f1W3,
                        const float* __restrict__ f2W0, const float* __restrict__ f2W1,
                        const float* __restrict__ f2W2, const float* __restrict__ f2W3,
                        float* __restrict__ ws, float* __restrict__ out) {
    _Float16* wh = (_Float16*)(ws + WS_H);
    const int blk = blockIdx.x, tid = threadIdx.x;
    if (blk < 256) {
        int wave = tid >> 6, lane = tid & 63;
        float vmax = -1e30f;
        for (int r = 0; r < 4; ++r) {
            int row = blk * 16 + wave * 4 + r;
            float v = 0.0f;
            for (int i = lane; i < 100; i += 64) v = fmaf(x_[row * 100 + i], lw[i], v);
            #pragma unroll
            for (int off = 32; off > 0; off >>= 1) v += __shfl_xor(v, off, 64);
            if (lane == 0) ws[WS_XM + row] = v;
            vmax = fmaxf(vmax, v);
        }
        __shared__ float sm[4];
        if (lane == 0) sm[wave] = vmax;
        __syncthreads();
        if (tid == 0)
            ws[WS_PM + blk] = fmaxf(fmaxf(sm[0], sm[1]), fmaxf(sm[2], sm[3]));
    } else if (blk < 272) {
        int t = (blk - 256) * 256 + tid;       // 0..4095
        wh[t]                = (_Float16)f1W1[t];
        wh[H_W2 + t]         = (_Float16)f1W2[t];
        wh[H_NET + t]        = (_Float16)f2W1[t];
        wh[H_NET + H_W2 + t] = (_Float16)f2W2[t];
        if (t < 2048) {
            int j = t >> 5, k = t & 31;
            wh[H_W0 + t]        = (k < 5) ? (_Float16)f1W0[j * 5 + k] : (_Float16)0.0f;
            wh[H_W0 + 2048 + t] = (k < 5) ? (_Float16)f2W0[j * 5 + k] : (_Float16)0.0f;
        }
        if (t < 64) {
            wh[H_W3 + t]      = (_Float16)f1W3[t];
            wh[H_W3 + 64 + t] = (_Float16)f2W3[t];
        }
    } else if (blk == 272) {
        if (tid == 64) ws[WS_LAM] = 1.0f / (1.0f + expf(-sp[0]));
        if (tid <= 50) {
            int s = tid;
            ws[WS_CCS + s] = cospif((float)s / 50.0f);
            float acc = 0.0f;
            for (int a = 0; a <= 50; ++a) {
                float w;
                if (a == 0) w = 1.0f;
                else if ((a & 1) == 0) w = 2.0f / (1.0f - (float)(a * a));
                else continue;
                float l;
                if (s == 0) l = 0.5f;
                else {
                    int m = (a * s) % 100;
                    l = cospif((float)m / 50.0f);
                    if (s == 50) l *= 0.5f;
                }
                acc += l * 0.04f * w;
            }
            ws[WS_CCW + s] = acc;
        }
    } else {
        // zero accumulation targets: out[0..BB) and out[2BB..3BB)
        int t = (blk - 273) * 256 + tid;       // 0..8191
        out[t < BB ? t : BB + t] = 0.0f;
    }
}

// between steps: x/x2 for step1, 16 partial maxes of x2, re-zero accumulators
__global__ void k_pre(float* __restrict__ ws, float* __restrict__ out) {
    int b = blockIdx.x * 256 + threadIdx.x;
    float lam = ws[WS_LAM];
    float m = ws[WS_XM + b];
    float xv  = (1.0f - lam) * m + lam * out[b];
    float x2v = (1.0f - lam) * m + lam * out[2 * BB + b];
    ws[WS_X + b] = xv;
    ws[WS_X2 + b] = x2v;
    out[b] = 0.0f;
    out[2 * BB + b] = 0.0f;
    __shared__ float red[256];
    red[threadIdx.x] = x2v;
    __syncthreads();
    #pragma unroll
    for (int off = 128; off > 0; off >>= 1) {
        if (threadIdx.x < off)
            red[threadIdx.x] = fmaxf(red[threadIdx.x], red[threadIdx.x + off]);
        __syncthreads();
    }
    if (threadIdx.x == 0) ws[WS_PM16 + blockIdx.x] = red[0];
}

// s-major: one MFMA pass = one CC point x 64 batch items. Group g (0..127)
// owns items [(g&63)*64, +64) for net (g>=64 ? f2 : f1); the 16 waves of a
// group take s = w, w+16, w+32, w+48. Lane owns item base+lane; acc in reg;
// one fp32 atomicAdd per item per wave. Blocks >=2048 (mode1): out_first,
// one pass, direct store.
__global__ __launch_bounds__(64, 2) void k_int(
    int mode, float* __restrict__ ws, const float* __restrict__ h_,
    const float* __restrict__ f1b0, const float* __restrict__ f1b1,
    const float* __restrict__ f1b2, const float* __restrict__ f1b3,
    const float* __restrict__ f1Wf,
    const float* __restrict__ f2b0, const float* __restrict__ f2b1,
    const float* __restrict__ f2b2, const float* __restrict__ f2b3,
    const float* __restrict__ f2Wf,
    float* __restrict__ out)
{
    __shared__ _Float16 act[64 * 64];     // 8 KB, single wave, barrier-free

    const int blk = blockIdx.x;
    const int lane = threadIdx.x;         // 0..63
    const int lo = lane & 15, q = lane >> 4;

    const float* xm = ws + WS_XM;
    const float* xarr = ws + WS_X;
    const float* x2arr = ws + WS_X2;
    const _Float16* wh = (const _Float16*)(ws + WS_H);
    const float lam = ws[WS_LAM];
    const float oml = 1.0f - lam;

    const bool is_of = (blk >= 2048);     // out_first block (mode 1 only)
    int base, w = 0, np;
    bool u2;
    if (is_of) {
        base = (blk - 2048) << 6; u2 = false; np = 1;
    } else {
        int g = blk >> 4;                 // 0..127
        w = blk & 15;                     // 0..15
        u2 = (g >= 64);
        base = (g & 63) << 6;
        np = (w < 3) ? 4 : 3;             // s = w,w+16,w+32[,w+48<=50]
    }

    const _Float16* W0h = wh + H_W0 + (u2 ? 2048 : 0);
    const _Float16* W1h = wh + (u2 ? H_NET : 0);
    const _Float16* W2h = W1h + H_W2;
    const _Float16* W3h = wh + H_W3 + (u2 ? 64 : 0);
    const float* B0 = u2 ? f2b0 : f1b0;
    const float* B1 = u2 ? f2b1 : f1b1;
    const float* B2 = u2 ? f2b2 : f1b2;
    const float* B3 = u2 ? f2b3 : f1b3;
    const float* WF = u2 ? f2Wf : f1Wf;
    const float p0 = u2 ? 1.5f : 1.1f;
    const float p1 = u2 ? 2.0f : 1.1f;
    const float p2 = u2 ? 2.5f : 1.5f;
    const float p3 = u2 ? 3.0f : 2.0f;
    const float p4 = u2 ? 3.5f : 2.5f;

    // ---- pin all weights/biases in registers (once per block) ----
    half8v A0w[4], A1w[4][2], A2w[4][2];
    float4v b0r[4], b1r[4], b2r[4];
    half4v w3r[4];
    #pragma unroll
    for (int m = 0; m < 4; ++m) {
        A0w[m]    = *(const half8v*)(W0h + (16 * m + lo) * 32 + q * 8);
        A1w[m][0] = *(const half8v*)(W1h + (16 * m + lo) * 64 + q * 8);
        A1w[m][1] = *(const half8v*)(W1h + (16 * m + lo) * 64 + 32 + q * 8);
        A2w[m][0] = *(const half8v*)(W2h + (16 * m + lo) * 64 + q * 8);
        A2w[m][1] = *(const half8v*)(W2h + (16 * m + lo) * 64 + 32 + q * 8);
        b0r[m] = *(const float4v*)(B0 + 16 * m + q * 4);
        b1r[m] = *(const float4v*)(B1 + 16 * m + q * 4);
        b2r[m] = *(const float4v*)(B2 + 16 * m + q * 4);
        w3r[m] = *(const half4v*)(W3h + 16 * m + 4 * q);
    }
    const float B3s = B3[0];
    const float wf0 = WF[0], wf1 = WF[1], wf2 = WF[2], wf3 = WF[3], wf4 = WF[4];

    // ---- per-lane item data: rows 16n+lo (B-build) / row lane (ownership) ----
    float xr_r[4];      // I1: xT; I2: x0; out_first: xin directly
    float4 h4r[4];
    #pragma unroll
    for (int n = 0; n < 4; ++n) {
        int idx = base + 16 * n + lo;
        float v;
        if (is_of)      v = x2arr[idx];
        else if (mode)  v = u2 ? x2arr[idx] : xarr[idx];
        else            v = oml * xm[idx];
        xr_r[n] = v;
        h4r[n] = ((const float4*)h_)[idx];
    }

    float xmax = 0.0f;
    if (u2) {
        if (mode) {
            float v = (lane < 16) ? ws[WS_PM16 + lane] : -1e30f;
            #pragma unroll
            for (int off = 32; off > 0; off >>= 1) v = fmaxf(v, __shfl_xor(v, off, 64));
            xmax = v + 10.0f;
        } else {
            const float* pm = ws + WS_PM;
            float v = fmaxf(fmaxf(pm[lane], pm[lane + 64]),
                            fmaxf(pm[lane + 128], pm[lane + 192]));
            #pragma unroll
            for (int off = 32; off > 0; off >>= 1) v = fmaxf(v, __shfl_xor(v, off, 64));
            xmax = oml * v + 10.0f;
        }
    }

    float acc = 0.0f;

    #pragma clang loop unroll(disable)
    for (int p = 0; p < np; ++p) {
        const int s = w + 16 * p;                       // <= 50 by construction
        float t = 0.0f, ccw_s = 0.0f;
        if (!is_of) {
            t = (ws[WS_CCS + s] + 1.0f) * 0.5f;
            ccw_s = ws[WS_CCW + s];
        }

        // build B-operand for layer 0 (only q==0 lanes carry k=0..4)
        half8v Bf0[4];
        #pragma unroll
        for (int n = 0; n < 4; ++n) {
            float xin;
            if (is_of)   xin = xr_r[n];
            else if (u2) xin = fmaf(t, xmax - xr_r[n], xr_r[n]);
            else         xin = xr_r[n] * t;
            half8v e;
            e[0] = (_Float16)xin; e[1] = (_Float16)h4r[n].x; e[2] = (_Float16)h4r[n].y;
            e[3] = (_Float16)h4r[n].z; e[4] = (_Float16)h4r[n].w;
            e[5] = (_Float16)0.0f; e[6] = (_Float16)0.0f; e[7] = (_Float16)0.0f;
            half8v z;
            #pragma unroll
            for (int t2 = 0; t2 < 8; ++t2) z[t2] = (_Float16)0.0f;
            Bf0[n] = (q == 0) ? e : z;
        }

        // ---- layer 0 ----
        #pragma unroll
        for (int m = 0; m < 4; ++m)
            #pragma unroll
            for (int n = 0; n < 4; ++n) {
                float4v c = __builtin_amdgcn_mfma_f32_16x16x32_f16(A0w[m], Bf0[n], b0r[m], 0, 0, 0);
                *(half4v*)(act + swz(16 * n + lo, 2 * m + (q >> 1)) + 4 * (q & 1)) = pk_relu4(c);
            }

        // ---- layer 1 ----
        {
            half8v Bf[2][4];
            #pragma unroll
            for (int kb = 0; kb < 2; ++kb)
                #pragma unroll
                for (int n = 0; n < 4; ++n)
                    Bf[kb][n] = *(const half8v*)(act + swz(16 * n + lo, 4 * kb + q));
            #pragma unroll
            for (int m = 0; m < 4; ++m)
                #pragma unroll
                for (int n = 0; n < 4; ++n) {
                    float4v c = __builtin_amdgcn_mfma_f32_16x16x32_f16(A1w[m][0], Bf[0][n], b1r[m], 0, 0, 0);
                    c = __builtin_amdgcn_mfma_f32_16x16x32_f16(A1w[m][1], Bf[1][n], c, 0, 0, 0);
                    *(half4v*)(act + swz(16 * n + lo, 2 * m + (q >> 1)) + 4 * (q & 1)) = pk_relu4(c);
                }
        }

        // ---- layer 2 with fused W3-dot ----
        float part[4] = {0.0f, 0.0f, 0.0f, 0.0f};
        {
            half8v Bf[2][4];
            #pragma unroll
            for (int kb = 0; kb < 2; ++kb)
                #pragma unroll
                for (int n = 0; n < 4; ++n)
                    Bf[kb][n] = *(const half8v*)(act + swz(16 * n + lo, 4 * kb + q));
            #pragma unroll
            for (int m = 0; m < 4; ++m)
                #pragma unroll
                for (int n = 0; n < 4; ++n) {
                    float4v c = __builtin_amdgcn_mfma_f32_16x16x32_f16(A2w[m][0], Bf[0][n], b2r[m], 0, 0, 0);
                    c = __builtin_amdgcn_mfma_f32_16x16x32_f16(A2w[m][1], Bf[1][n], c, 0, 0, 0);
                    #pragma unroll
                    for (int e = 0; e < 4; ++e)
                        part[n] = fmaf((float)w3r[m][e], fmaxf(c[e], 0.0f), part[n]);
                }
        }

        // complete each row's dot across quads; lane keeps its own row (=lane)
        #pragma unroll
        for (int n = 0; n < 4; ++n) {
            part[n] += __shfl_xor(part[n], 16, 64);
            part[n] += __shfl_xor(part[n], 32, 64);
        }
        float y = B3s + (q == 0 ? part[0] : q == 1 ? part[1] : q == 2 ? part[2] : part[3]);

        if (y <= 0.0f) y = FEXP2(y * 1.44269504f) - 1.0f;   // elu
        float z = y + 1.0f;
        float lg = FLOG2(z);
        float g = wf0 * FRCP(FEXP2(p0 * lg) + 1.0f)
                + wf1 * FRCP(FEXP2(p1 * lg) + 1.0f)
                + wf2 * FRCP(FEXP2(p2 * lg) + 1.0f)
                + wf3 * FRCP(FEXP2(p3 * lg) + 1.0f)
                + wf4 * FRCP(FEXP2(p4 * lg) + 1.0f);
        float val = fmaxf(g, 0.0f);

        if (is_of) { out[BB + base + lane] = val; return; }
        acc += ccw_s * val;
    }

    // ---- per-item epilogue: lane owns item base+lane (row 16q+lo == lane) ----
    const float x_l = (q == 0 ? xr_r[0] : q == 1 ? xr_r[1] : q == 2 ? xr_r[2] : xr_r[3]);
    if (!u2) {
        atomicAdd(out + base + lane, acc * x_l * 0.5f);
    } else {
        atomicAdd(out + 2 * BB + base + lane, acc * (xmax - x_l) * 0.5f * INV_ALPHA);
    }
}

extern "C" void kernel_launch(void* const* d_in, const int* in_sizes, int n_in,
                              void* d_out, int out_size, void* d_ws, size_t ws_size,
                              hipStream_t stream) {
    const float* x_  = (const float*)d_in[0];
    const float* h_  = (const float*)d_in[1];
    const float* lw  = (const float*)d_in[2];
    const float* sp  = (const float*)d_in[3];
    const float* f1W0 = (const float*)d_in[4];   const float* f1b0 = (const float*)d_in[5];
    const float* f1W1 = (const float*)d_in[6];   const float* f1b1 = (const float*)d_in[7];
    const float* f1W2 = (const float*)d_in[8];   const float* f1b2 = (const float*)d_in[9];
    const float* f1W3 = (const float*)d_in[10];  const float* f1b3 = (const float*)d_in[11];
    const float* f1Wf = (const float*)d_in[12];
    const float* f2W0 = (const float*)d_in[13];  const float* f2b0 = (const float*)d_in[14];
    const float* f2W1 = (const float*)d_in[15];  const float* f2b1 = (const float*)d_in[16];
    const float* f2W2 = (const float*)d_in[17];  const float* f2b2 = (const float*)d_in[18];
    const float* f2W3 = (const float*)d_in[19];  const float* f2b3 = (const float*)d_in[20];
    const float* f2Wf = (const float*)d_in[21];
    float* out = (float*)d_out;
    float* ws  = (float*)d_ws;

    k_setup<<<305, 256, 0, stream>>>(x_, lw, sp,
                                     f1W0, f1W1, f1W2, f1W3,
                                     f2W0, f2W1, f2W2, f2W3, ws, out);
    k_int<<<2048, 64, 0, stream>>>(0, ws, h_,
        f1b0, f1b1, f1b2, f1b3, f1Wf, f2b0, f2b1, f2b2, f2b3, f2Wf, out);
    k_pre<<<16, 256, 0, stream>>>(ws, out);
    k_int<<<2112, 64, 0, stream>>>(1, ws, h_,
        f1b0, f1b1, f1b2, f1b3, f1Wf, f2b0, f2b1, f2b2, f2b3, f2Wf, out);
}